// Round 2
// baseline (6709.650 us; speedup 1.0000x reference)
//
#include <hip/hip_runtime.h>
#include <stdint.h>

// RNN LM: embed->shift -> 2-layer tanh RNN (T=2048) -> logits vs embedding^T
//         -> log_softmax -> gather at tokens -> sum (scalar out).
//
// k_rnn R3: register dataflow. Spin loads deliver h wave-partitioned into
// VGPRs (wave w owns a contiguous k-chunk). Each lane computes 32 column
// partials over its own 4/6 h-values vs resident weights, then a wave-level
// reduce-scatter (shfl_xor butterfly, value count halves per step) yields one
// column sum per lane-pair. Tiny LDS combine (stride-5, conflict-free) + one
// barrier + 32 finalists do tanh + packed u64 store. No bulk LDS staging.

#define TSEQ 2048
#define NVOCAB 32000
#define DEMB 512
#define DHID 1024
#define CAN 0xFFFFFFFFu

typedef __attribute__((ext_vector_type(8))) short short8;
typedef __attribute__((ext_vector_type(4))) float f32x4;
typedef unsigned long long u64;

__device__ __forceinline__ unsigned short f2bf(float f) {
  union { float f; unsigned u; } v; v.f = f;
  unsigned r = (v.u + 0x7FFFu + ((v.u >> 16) & 1u)) >> 16;
  return (unsigned short)r;
}

// wave reduce-scatter over 32 values: on return, lanes l and l^1 hold the
// full 64-lane sum for column (l>>1)&31.
__device__ __forceinline__ float rscatter32(float (&p)[32], int l) {
#pragma unroll
  for (int j = 0; j < 16; ++j) {
    float a = p[j]      + __shfl_xor(p[j],      32);
    float b = p[j + 16] + __shfl_xor(p[j + 16], 32);
    p[j] = (l & 32) ? b : a;
  }
#pragma unroll
  for (int j = 0; j < 8; ++j) {
    float a = p[j]     + __shfl_xor(p[j],     16);
    float b = p[j + 8] + __shfl_xor(p[j + 8], 16);
    p[j] = (l & 16) ? b : a;
  }
#pragma unroll
  for (int j = 0; j < 4; ++j) {
    float a = p[j]     + __shfl_xor(p[j],     8);
    float b = p[j + 4] + __shfl_xor(p[j + 4], 8);
    p[j] = (l & 8) ? b : a;
  }
#pragma unroll
  for (int j = 0; j < 2; ++j) {
    float a = p[j]     + __shfl_xor(p[j],     4);
    float b = p[j + 2] + __shfl_xor(p[j + 2], 4);
    p[j] = (l & 4) ? b : a;
  }
  {
    float a = p[0] + __shfl_xor(p[0], 2);
    float b = p[1] + __shfl_xor(p[1], 2);
    p[0] = (l & 2) ? b : a;
  }
  return p[0] + __shfl_xor(p[0], 1);
}

// ---------------- init: poison all slots; slot 0 = real zeros ----------------
__global__ void k_init(uint4* __restrict__ h1v4, uint4* __restrict__ h2v4) {
  const int n1 = (TSEQ + 1) * DHID / 4;
  const int n2 = (TSEQ + 1) * DEMB / 4;
  uint4 can; can.x = CAN; can.y = CAN; can.z = CAN; can.w = CAN;
  uint4 zer; zer.x = 0u; zer.y = 0u; zer.z = 0u; zer.w = 0u;
  const int stride = gridDim.x * blockDim.x;
  for (int i = blockIdx.x * blockDim.x + threadIdx.x; i < n1 + n2; i += stride) {
    if (i < n1) {
      h1v4[i] = (i < DHID / 4) ? zer : can;
    } else {
      int j = i - n1;
      h2v4[j] = (j < DEMB / 4) ? zer : can;
    }
  }
}

// ---------------- xW1[t][j] = b1[j] + sum_e inputs[t][e]*W1[e][j] ------------
__global__ __launch_bounds__(256) void k_xw1(const int* __restrict__ tok,
                                             const float* __restrict__ emb,
                                             const float* __restrict__ W1,
                                             const float* __restrict__ b1,
                                             float* __restrict__ xW1) {
  __shared__ float in_lds[16 * DEMB];
  const int tid = threadIdx.x;
  const int rb = blockIdx.x >> 2, cb = blockIdx.x & 3;
  const int t0 = rb * 16, j0 = cb * 256;
  for (int idx = tid; idx < 16 * 128; idx += 256) {
    int r = idx >> 7, q = idx & 127;
    int t = t0 + r;
    float4 v;
    if (t == 0) { v.x = 0.f; v.y = 0.f; v.z = 0.f; v.w = 0.f; }
    else        { v = *(const float4*)(emb + (size_t)tok[t - 1] * DEMB + q * 4); }
    *(float4*)&in_lds[r * DEMB + q * 4] = v;
  }
  __syncthreads();
  const int j = j0 + tid;
  float acc[16];
  {
    float bb = b1[j];
#pragma unroll
    for (int r = 0; r < 16; ++r) acc[r] = bb;
  }
  for (int k = 0; k < DEMB; k += 4) {
    const float* wp = W1 + (size_t)k * DHID + j;
    float w0 = wp[0], w1 = wp[DHID], w2 = wp[2 * DHID], w3 = wp[3 * DHID];
#pragma unroll
    for (int r = 0; r < 16; ++r) {
      float4 h = *(const float4*)&in_lds[r * DEMB + k];
      acc[r] += h.x * w0;
      acc[r] += h.y * w1;
      acc[r] += h.z * w2;
      acc[r] += h.w * w3;
    }
  }
#pragma unroll
  for (int r = 0; r < 16; ++r) xW1[(size_t)(t0 + r) * DHID + j] = acc[r];
}

// ---------------- persistent RNN, register dataflow ----------------
// 48 WGs x 256 thr. WG 0..31: layer1 (32 cols each). WG 32..47: layer2.
// wave wv (0..3) owns k-chunk [256*wv,256*wv+256) (L1) / [384*wv,+384) (L2);
// lane l owns 4 (L1) / 6 (L2) consecutive k within the chunk.
__global__ __launch_bounds__(256, 1) void k_rnn(const float* __restrict__ xW1,
                                                const float* __restrict__ U1,
                                                const float* __restrict__ W2,
                                                const float* __restrict__ U2,
                                                const float* __restrict__ b2,
                                                u64* __restrict__ h1v,
                                                u64* __restrict__ h2v,
                                                float* __restrict__ h2buf) {
  __shared__ float cmb[2][160];   // [parity][col*5 + wave], stride-5 pad
  const int tid = threadIdx.x;
  const int wg = blockIdx.x;
  const int l = tid & 63, wv = tid >> 6;

  if (wg < 32) {  // ---- layer 1: h1[t] = tanh(xW1[t] + h1[t-1]@U1) ----
    const int c0 = wg * 32;
    // weights: wr[j*4+i] = U1[256*wv + 4*l + i][c0+j]
    float wr[128];
#pragma unroll
    for (int i = 0; i < 4; ++i) {
      const float* up = U1 + (size_t)(256 * wv + 4 * l + i) * DHID + c0;
#pragma unroll
      for (int j = 0; j < 32; ++j) wr[j * 4 + i] = up[j];
    }
    const float* xp = xW1 + c0 + tid;            // finalists only (tid<32)
    const u64* src = h1v + 2 * tid;              // step 0 reads slot 0
    u64* dst = h1v + (size_t)DHID / 2 + ((c0 + tid) >> 1);
    for (int st = 0; st < TSEQ; ++st) {
      float xv = 0.f;
      if (tid < 32) xv = *xp;
      u64 a0, a1;
      bool d0 = false, d1 = false;
      while (true) {  // per-thread spin
        u64 x0, x1;
        if (!d0) x0 = __hip_atomic_load(src + 0, __ATOMIC_RELAXED, __HIP_MEMORY_SCOPE_AGENT);
        if (!d1) x1 = __hip_atomic_load(src + 1, __ATOMIC_RELAXED, __HIP_MEMORY_SCOPE_AGENT);
        if (!d0 && (unsigned)(x0 >> 32) != CAN) { a0 = x0; d0 = true; }
        if (!d1 && (unsigned)(x1 >> 32) != CAN) { a1 = x1; d1 = true; }
        if (d0 && d1) break;
      }
      float hk0 = __uint_as_float((unsigned)a0);
      float hk1 = __uint_as_float((unsigned)(a0 >> 32));
      float hk2 = __uint_as_float((unsigned)a1);
      float hk3 = __uint_as_float((unsigned)(a1 >> 32));
      float acc[32];
#pragma unroll
      for (int j = 0; j < 32; ++j) {
        acc[j] = hk0 * wr[j * 4 + 0] + hk1 * wr[j * 4 + 1] +
                 hk2 * wr[j * 4 + 2] + hk3 * wr[j * 4 + 3];
      }
      float r = rscatter32(acc, l);
      const int par = st & 1;
      if ((l & 1) == 0) cmb[par][((l >> 1) & 31) * 5 + wv] = r;
      __syncthreads();
      if (tid < 32) {
        const float* cp = &cmb[par][tid * 5];
        float s4 = (cp[0] + cp[1]) + (cp[2] + cp[3]);
        float hv = tanhf(xv + s4);
        float hv2 = __shfl_down(hv, 1);
        if ((tid & 1) == 0) {
          u64 pk = ((u64)__float_as_uint(hv2) << 32) | (u64)__float_as_uint(hv);
          __hip_atomic_store(dst, pk, __ATOMIC_RELAXED, __HIP_MEMORY_SCOPE_AGENT);
        }
      }
      src += DHID / 2;
      dst += DHID / 2;
      xp += DHID;
    }
  } else {  // ---- layer 2: h2[j] = tanh(h1[j]@W2 + h2[j-1]@U2 + b2) ----
    const int c0 = (wg - 32) * 32;
    // weights: wr[j*6+i] = M[384*wv + 6*l + i][c0+j], M = [W2;U2]
    float wr[192];
#pragma unroll
    for (int i = 0; i < 6; ++i) {
      int k = 384 * wv + 6 * l + i;
      const float* mp = (k < DHID) ? (W2 + (size_t)k * DEMB)
                                   : (U2 + (size_t)(k - DHID) * DEMB);
#pragma unroll
      for (int j = 0; j < 32; ++j) wr[j * 6 + i] = mp[c0 + j];
    }
    float bias = 0.f;
    if (tid < 32) bias = b2[c0 + tid];
    // spin sources: u64 index p = 3*tid+q over concat [h1:512 u64 | h2:256 u64]
    const int p0 = 3 * tid, p1 = 3 * tid + 1, p2 = 3 * tid + 2;
    const u64* s0 = (p0 < DHID / 2) ? h1v + DHID / 2 + p0 : h2v + (p0 - DHID / 2);
    const u64* s1 = (p1 < DHID / 2) ? h1v + DHID / 2 + p1 : h2v + (p1 - DHID / 2);
    const u64* s2 = (p2 < DHID / 2) ? h1v + DHID / 2 + p2 : h2v + (p2 - DHID / 2);
    const ptrdiff_t i0 = (p0 < DHID / 2) ? DHID / 2 : DEMB / 2;
    const ptrdiff_t i1 = (p1 < DHID / 2) ? DHID / 2 : DEMB / 2;
    const ptrdiff_t i2 = (p2 < DHID / 2) ? DHID / 2 : DEMB / 2;
    u64* dst = h2v + (size_t)DEMB / 2 + ((c0 + tid) >> 1);
    float* hbuf = h2buf + DEMB + c0 + tid;
    for (int j2 = 0; j2 < TSEQ; ++j2) {
      u64 a0, a1, a2;
      bool d0 = false, d1 = false, d2 = false;
      while (true) {  // per-thread spin
        u64 x0, x1, x2;
        if (!d0) x0 = __hip_atomic_load(s0, __ATOMIC_RELAXED, __HIP_MEMORY_SCOPE_AGENT);
        if (!d1) x1 = __hip_atomic_load(s1, __ATOMIC_RELAXED, __HIP_MEMORY_SCOPE_AGENT);
        if (!d2) x2 = __hip_atomic_load(s2, __ATOMIC_RELAXED, __HIP_MEMORY_SCOPE_AGENT);
        if (!d0 && (unsigned)(x0 >> 32) != CAN) { a0 = x0; d0 = true; }
        if (!d1 && (unsigned)(x1 >> 32) != CAN) { a1 = x1; d1 = true; }
        if (!d2 && (unsigned)(x2 >> 32) != CAN) { a2 = x2; d2 = true; }
        if (d0 && d1 && d2) break;
      }
      float hk0 = __uint_as_float((unsigned)a0);
      float hk1 = __uint_as_float((unsigned)(a0 >> 32));
      float hk2 = __uint_as_float((unsigned)a1);
      float hk3 = __uint_as_float((unsigned)(a1 >> 32));
      float hk4 = __uint_as_float((unsigned)a2);
      float hk5 = __uint_as_float((unsigned)(a2 >> 32));
      float acc[32];
#pragma unroll
      for (int j = 0; j < 32; ++j) {
        acc[j] = hk0 * wr[j * 6 + 0] + hk1 * wr[j * 6 + 1] +
                 hk2 * wr[j * 6 + 2] + hk3 * wr[j * 6 + 3] +
                 hk4 * wr[j * 6 + 4] + hk5 * wr[j * 6 + 5];
      }
      float r = rscatter32(acc, l);
      const int par = j2 & 1;
      if ((l & 1) == 0) cmb[par][((l >> 1) & 31) * 5 + wv] = r;
      __syncthreads();
      if (tid < 32) {
        const float* cp = &cmb[par][tid * 5];
        float s4 = (cp[0] + cp[1]) + (cp[2] + cp[3]);
        float hv = tanhf(s4 + bias);
        float hv2 = __shfl_down(hv, 1);
        if ((tid & 1) == 0) {
          u64 pk = ((u64)__float_as_uint(hv2) << 32) | (u64)__float_as_uint(hv);
          __hip_atomic_store(dst, pk, __ATOMIC_RELAXED, __HIP_MEMORY_SCOPE_AGENT);
          float2 st2; st2.x = hv; st2.y = hv2;
          *(float2*)hbuf = st2;
        }
      }
      s0 += i0; s1 += i1; s2 += i2;
      dst += DEMB / 2;
      hbuf += DEMB;
    }
  }
}

// ---------------- f32 -> bf16 casts (embedding + h2 history) ----------------
__global__ void k_conv(const float* __restrict__ emb, const float* __restrict__ h2f,
                       unsigned short* __restrict__ embB, unsigned short* __restrict__ h2b) {
  const int n1 = NVOCAB * DEMB / 4;
  const int n2 = TSEQ * DEMB / 4;
  const int stride = gridDim.x * blockDim.x;
  for (int i = blockIdx.x * blockDim.x + threadIdx.x; i < n1 + n2; i += stride) {
    float4 v;
    if (i < n1) v = ((const float4*)emb)[i];
    else        v = ((const float4*)h2f)[i - n1];
    ushort4 o;
    o.x = f2bf(v.x); o.y = f2bf(v.y); o.z = f2bf(v.z); o.w = f2bf(v.w);
    if (i < n1) ((ushort4*)embB)[i] = o;
    else        ((ushort4*)h2b)[i - n1] = o;
  }
}

// ---------------- fused logits GEMM + online softmax stats ----------------
__global__ __launch_bounds__(256, 1) void k_logits(const unsigned short* __restrict__ Ab,
                                                   const unsigned short* __restrict__ Bb,
                                                   float* __restrict__ pmax,
                                                   float* __restrict__ psum) {
  extern __shared__ char smem_dyn[];
  unsigned short* As = (unsigned short*)smem_dyn;       // 128*512*2 = 131072 B
  float* sstat = (float*)(smem_dyn + 131072);           // 4*128*2 f32
  const int tid = threadIdx.x;
  const int rb = blockIdx.x >> 4, ch = blockIdx.x & 15;
  const int r0 = rb * 128, v0 = ch * 2000;
  for (int idx = tid; idx < 128 * 64; idx += 256) {
    int row = idx >> 6, kq = idx & 63;
    uint4 v = *(const uint4*)(Ab + (size_t)(r0 + row) * DEMB + kq * 8);
    int byte = (row * 1024 + kq * 16) ^ ((row & 7) << 4);
    *(uint4*)((char*)As + byte) = v;
  }
  __syncthreads();
  const int wv = tid >> 6, lane = tid & 63;
  const int col = lane & 15, kg = lane >> 4;
  f32x4 rmax[8], rsum[8];
#pragma unroll
  for (int t = 0; t < 8; ++t) { rmax[t] = (f32x4)(-3.0e38f); rsum[t] = (f32x4)(0.f); }

  for (int strip = wv; strip < 125; strip += 4) {
    const unsigned short* bp = Bb + (size_t)(v0 + strip * 16 + col) * DEMB + kg * 8;
    f32x4 acc[8];
#pragma unroll
    for (int t = 0; t < 8; ++t) acc[t] = (f32x4)(0.f);
#pragma unroll
    for (int ks = 0; ks < 16; ++ks) {
      short8 bfrag = *(const short8*)(bp + ks * 32);
#pragma unroll
      for (int t = 0; t < 8; ++t) {
        int row = t * 16 + col;
        int byte = (row * 1024 + ks * 64 + kg * 16) ^ ((row & 7) << 4);
        short8 afrag = *(const short8*)((const char*)As + byte);
        acc[t] = __builtin_amdgcn_mfma_f32_16x16x32_bf16(afrag, bfrag, acc[t], 0, 0, 0);
      }
    }
#pragma unroll
    for (int t = 0; t < 8; ++t) {
      f32x4 v = acc[t];
      f32x4 mx = v;
#pragma unroll
      for (int d = 1; d < 16; d <<= 1) {
        mx.x = fmaxf(mx.x, __shfl_xor(mx.x, d));
        mx.y = fmaxf(mx.y, __shfl_xor(mx.y, d));
        mx.z = fmaxf(mx.z, __shfl_xor(mx.z, d));
        mx.w = fmaxf(mx.w, __shfl_xor(mx.w, d));
      }
      f32x4 nm;
      nm.x = fmaxf(rmax[t].x, mx.x);
      nm.y = fmaxf(rmax[t].y, mx.y);
      nm.z = fmaxf(rmax[t].z, mx.z);
      nm.w = fmaxf(rmax[t].w, mx.w);
      f32x4 e;
      e.x = __expf(v.x - nm.x); e.y = __expf(v.y - nm.y);
      e.z = __expf(v.z - nm.z); e.w = __expf(v.w - nm.w);
#pragma unroll
      for (int d = 1; d < 16; d <<= 1) {
        e.x += __shfl_xor(e.x, d);
        e.y += __shfl_xor(e.y, d);
        e.z += __shfl_xor(e.z, d);
        e.w += __shfl_xor(e.w, d);
      }
      rsum[t].x = rsum[t].x * __expf(rmax[t].x - nm.x) + e.x;
      rsum[t].y = rsum[t].y * __expf(rmax[t].y - nm.y) + e.y;
      rsum[t].z = rsum[t].z * __expf(rmax[t].z - nm.z) + e.z;
      rsum[t].w = rsum[t].w * __expf(rmax[t].w - nm.w) + e.w;
      rmax[t] = nm;
    }
  }
  if (col == 0) {
#pragma unroll
    for (int t = 0; t < 8; ++t) {
#pragma unroll
      for (int r = 0; r < 4; ++r) {
        int row = t * 16 + kg * 4 + r;
        sstat[(wv * 128 + row) * 2 + 0] = rmax[t][r];
        sstat[(wv * 128 + row) * 2 + 1] = rsum[t][r];
      }
    }
  }
  __syncthreads();
  if (tid < 128) {
    float m = -3.0e38f, ssum = 0.f;
#pragma unroll
    for (int w2 = 0; w2 < 4; ++w2) {
      float pm = sstat[(w2 * 128 + tid) * 2 + 0];
      float ps = sstat[(w2 * 128 + tid) * 2 + 1];
      float nm2 = fmaxf(m, pm);
      ssum = ssum * __expf(m - nm2) + ps * __expf(pm - nm2);
      m = nm2;
    }
    pmax[(size_t)(r0 + tid) * 16 + ch] = m;
    psum[(size_t)(r0 + tid) * 16 + ch] = ssum;
  }
}

// ---------------- target logit in f32: dot(h2[t], emb[tok[t]]) ----------------
__global__ __launch_bounds__(256) void k_tlogit(const int* __restrict__ tok,
                                                const float* __restrict__ emb,
                                                const float* __restrict__ h2buf,
                                                float* __restrict__ tlog) {
  const int wv = threadIdx.x >> 6, lane = threadIdx.x & 63;
  const int wgid = blockIdx.x * 4 + wv;
  for (int t = wgid; t < TSEQ; t += 128) {
    const float* hp = h2buf + (size_t)(t + 1) * DEMB + lane * 8;
    const float* ep = emb + (size_t)tok[t] * DEMB + lane * 8;
    float4 h0 = *(const float4*)hp, h1v = *(const float4*)(hp + 4);
    float4 e0 = *(const float4*)ep, e1v = *(const float4*)(ep + 4);
    float d = h0.x * e0.x + h0.y * e0.y + h0.z * e0.z + h0.w * e0.w +
              h1v.x * e1v.x + h1v.y * e1v.y + h1v.z * e1v.z + h1v.w * e1v.w;
    for (int m = 1; m < 64; m <<= 1) d += __shfl_xor(d, m);
    if (lane == 0) tlog[t] = d;
  }
}

// ---------------- final: sum_t (tlogit - lse) ----------------
__global__ void k_final(const float* __restrict__ pmax, const float* __restrict__ psum,
                        const float* __restrict__ tlog, float* __restrict__ out) {
  __shared__ float red[4];
  float local = 0.f;
  for (int t = threadIdx.x; t < TSEQ; t += 256) {
    float m = -3.0e38f, s = 0.f;
#pragma unroll
    for (int c = 0; c < 16; ++c) {
      float pm = pmax[t * 16 + c], ps = psum[t * 16 + c];
      float nm = fmaxf(m, pm);
      s = s * __expf(m - nm) + ps * __expf(pm - nm);
      m = nm;
    }
    local += tlog[t] - (m + __logf(s));
  }
  for (int d = 1; d < 64; d <<= 1) local += __shfl_xor(local, d);
  if ((threadIdx.x & 63) == 0) red[threadIdx.x >> 6] = local;
  __syncthreads();
  if (threadIdx.x == 0) out[0] = red[0] + red[1] + red[2] + red[3];
}

// ---------------- host ----------------
extern "C" void kernel_launch(void* const* d_in, const int* in_sizes, int n_in,
                              void* d_out, int out_size, void* d_ws, size_t ws_size,
                              hipStream_t stream) {
  (void)in_sizes; (void)n_in; (void)out_size; (void)ws_size;
  const int*   tok = (const int*)d_in[0];
  const float* emb = (const float*)d_in[1];
  const float* W1  = (const float*)d_in[2];
  const float* U1  = (const float*)d_in[3];
  const float* b1  = (const float*)d_in[4];
  const float* W2  = (const float*)d_in[5];
  const float* U2  = (const float*)d_in[6];
  const float* b2  = (const float*)d_in[7];
  float* out = (float*)d_out;

  char* ws = (char*)d_ws;
  size_t off = 0;
  auto alloc = [&](size_t bytes) {
    char* p = ws + off;
    off = (off + bytes + 255) & ~(size_t)255;
    return p;
  };
  float* h2buf = (float*)alloc((size_t)(TSEQ + 1) * DEMB * 4);
  unsigned short* h2b = (unsigned short*)alloc((size_t)TSEQ * DEMB * 2);
  float* pmax = (float*)alloc((size_t)TSEQ * 16 * 4);
  float* psum = (float*)alloc((size_t)TSEQ * 16 * 4);
  float* tlog = (float*)alloc((size_t)TSEQ * 4);
  // big region: [h2v][h1v][xW1] during k_rnn; embB (32.77MB) overlays from
  // offset 0 afterwards. Safe because k_init re-poisons all h slots at the
  // start of every launch before k_rnn runs.
  size_t sz_h2v = (size_t)(TSEQ + 1) * DEMB * 4;   //  4,196,352
  size_t sz_h1v = (size_t)(TSEQ + 1) * DHID * 4;   //  8,392,704
  size_t sz_xw1 = (size_t)TSEQ * DHID * 4;         //  8,388,608
  size_t sz_embB = (size_t)NVOCAB * DEMB * 2;      // 32,768,000
  size_t big_sz = sz_h2v + sz_h1v + sz_xw1;
  if (sz_embB > big_sz) big_sz = sz_embB;
  char* big = alloc(big_sz);
  float* h2v = (float*)big;
  float* h1v = (float*)(big + sz_h2v);
  float* xW1 = (float*)(big + sz_h2v + sz_h1v);
  unsigned short* embB = (unsigned short*)big;

  k_init<<<dim3(512), dim3(256), 0, stream>>>((uint4*)h1v, (uint4*)h2v);
  k_xw1<<<dim3(512), dim3(256), 0, stream>>>(tok, emb, W1, b1, xW1);
  k_rnn<<<dim3(48), dim3(256), 0, stream>>>(xW1, U1, W2, U2, b2,
                                            (u64*)h1v, (u64*)h2v, h2buf);
  k_conv<<<dim3(2048), dim3(256), 0, stream>>>(emb, h2buf + DEMB, embB, h2b);
  k_logits<<<dim3(256), dim3(256), 135168, stream>>>(h2b, embB, pmax, psum);
  k_tlogit<<<dim3(32), dim3(256), 0, stream>>>(tok, emb, h2buf, tlog);
  k_final<<<dim3(1), dim3(256), 0, stream>>>(pmax, psum, tlog, out);
}

// Round 3
// 4391.639 us; speedup vs baseline: 1.5278x; 1.5278x over previous
//
#include <hip/hip_runtime.h>
#include <stdint.h>

// RNN LM: embed->shift -> 2-layer tanh RNN (T=2048) -> logits vs embedding^T
//         -> log_softmax -> gather at tokens -> sum (scalar out).
//
// k_rnn R4: DPP-systolic dot, canary dataflow.
//  - h state arrays are plain f32, poisoned to 0xFFFFFFFF (NaN pattern) by
//    k_init; producers publish 16B (4 adjacent cols) via global_store_dwordx4
//    sc0 sc1; consumers poll their own 16B quad via global_load_dwordx4
//    sc0 sc1 (per-word canaries tolerate torn 16B visibility).
//  - dot: each lane holds its polled quad; 16-step row_ror:1 DPP rotation
//    with PRE-PERMUTED weights (wA[4j+e] = W[k(4*((i-j)&15)+e)][col]) lets
//    each lane accumulate 2 columns over its row's 64 k with no LDS staging.
//    Cross-row: 2x shfl_xor. Cross-wave: 128-float padded LDS + 1 barrier.
//  - layer2 two-phase: h1-region dot (available early) + joint h1/h2 spin
//    with both loads in flight; h2-region dot on waves 0-1 only.
//  - fast tanh: 1 - 2/(e^{2|x|}+1), sign-restored (tolerance absorbs).

#define TSEQ 2048
#define NVOCAB 32000
#define DEMB 512
#define DHID 1024
#define CAN 0xFFFFFFFFu

typedef __attribute__((ext_vector_type(8))) short short8;
typedef __attribute__((ext_vector_type(4))) float f32x4;
typedef unsigned long long u64;

__device__ __forceinline__ unsigned short f2bf(float f) {
  union { float f; unsigned u; } v; v.f = f;
  unsigned r = (v.u + 0x7FFFu + ((v.u >> 16) & 1u)) >> 16;
  return (unsigned short)r;
}

__device__ __forceinline__ f32x4 llc_ld16(const float* p) {
  f32x4 r;
  asm volatile("global_load_dwordx4 %0, %1, off sc0 sc1\n\ts_waitcnt vmcnt(0)"
               : "=&v"(r) : "v"(p) : "memory");
  return r;
}

__device__ __forceinline__ void llc_ld16x2(const float* pa, const float* pb,
                                           f32x4& a, f32x4& b) {
  asm volatile("global_load_dwordx4 %0, %2, off sc0 sc1\n\t"
               "global_load_dwordx4 %1, %3, off sc0 sc1\n\t"
               "s_waitcnt vmcnt(0)"
               : "=&v"(a), "=&v"(b) : "v"(pa), "v"(pb) : "memory");
}

__device__ __forceinline__ void llc_st16(float* p, f32x4 v) {
  asm volatile("global_store_dwordx4 %0, %1, off sc0 sc1"
               :: "v"(p), "v"(v) : "memory");
}

__device__ __forceinline__ bool okq(f32x4 v) {
  return __float_as_uint(v.x) != CAN && __float_as_uint(v.y) != CAN &&
         __float_as_uint(v.z) != CAN && __float_as_uint(v.w) != CAN;
}

// rotate quad right by 1 lane within each 16-lane row (row_ror:1 = 0x121):
// after j applications, lane i holds the quad originally at lane (i-j)&15.
__device__ __forceinline__ f32x4 rotq(f32x4 h) {
  f32x4 r;
  r.x = __int_as_float(__builtin_amdgcn_mov_dpp(__float_as_int(h.x), 0x121, 0xf, 0xf, false));
  r.y = __int_as_float(__builtin_amdgcn_mov_dpp(__float_as_int(h.y), 0x121, 0xf, 0xf, false));
  r.z = __int_as_float(__builtin_amdgcn_mov_dpp(__float_as_int(h.z), 0x121, 0xf, 0xf, false));
  r.w = __int_as_float(__builtin_amdgcn_mov_dpp(__float_as_int(h.w), 0x121, 0xf, 0xf, false));
  return r;
}

__device__ __forceinline__ float tanh_fast(float x) {
  float ax = fabsf(x);
  float e = __expf(ax + ax);               // inf for large ax -> t = 1 (correct)
  float t = 1.f - __fdividef(2.f, e + 1.f);
  return (x < 0.f) ? -t : t;
}

// ---------------- init: poison all slots; slot 0 = real zeros ----------------
__global__ void k_init(uint4* __restrict__ h1v4, uint4* __restrict__ h2v4) {
  const int n1 = (TSEQ + 1) * DHID / 4;
  const int n2 = (TSEQ + 1) * DEMB / 4;
  uint4 can; can.x = CAN; can.y = CAN; can.z = CAN; can.w = CAN;
  uint4 zer; zer.x = 0u; zer.y = 0u; zer.z = 0u; zer.w = 0u;
  const int stride = gridDim.x * blockDim.x;
  for (int i = blockIdx.x * blockDim.x + threadIdx.x; i < n1 + n2; i += stride) {
    if (i < n1) {
      h1v4[i] = (i < DHID / 4) ? zer : can;
    } else {
      int j = i - n1;
      h2v4[j] = (j < DEMB / 4) ? zer : can;
    }
  }
}

// ---------------- xW1[t][j] = b1[j] + sum_e inputs[t][e]*W1[e][j] ------------
__global__ __launch_bounds__(256) void k_xw1(const int* __restrict__ tok,
                                             const float* __restrict__ emb,
                                             const float* __restrict__ W1,
                                             const float* __restrict__ b1,
                                             float* __restrict__ xW1) {
  __shared__ float in_lds[16 * DEMB];
  const int tid = threadIdx.x;
  const int rb = blockIdx.x >> 2, cb = blockIdx.x & 3;
  const int t0 = rb * 16, j0 = cb * 256;
  for (int idx = tid; idx < 16 * 128; idx += 256) {
    int r = idx >> 7, q = idx & 127;
    int t = t0 + r;
    float4 v;
    if (t == 0) { v.x = 0.f; v.y = 0.f; v.z = 0.f; v.w = 0.f; }
    else        { v = *(const float4*)(emb + (size_t)tok[t - 1] * DEMB + q * 4); }
    *(float4*)&in_lds[r * DEMB + q * 4] = v;
  }
  __syncthreads();
  const int j = j0 + tid;
  float acc[16];
  {
    float bb = b1[j];
#pragma unroll
    for (int r = 0; r < 16; ++r) acc[r] = bb;
  }
  for (int k = 0; k < DEMB; k += 4) {
    const float* wp = W1 + (size_t)k * DHID + j;
    float w0 = wp[0], w1 = wp[DHID], w2 = wp[2 * DHID], w3 = wp[3 * DHID];
#pragma unroll
    for (int r = 0; r < 16; ++r) {
      float4 h = *(const float4*)&in_lds[r * DEMB + k];
      acc[r] += h.x * w0;
      acc[r] += h.y * w1;
      acc[r] += h.z * w2;
      acc[r] += h.w * w3;
    }
  }
#pragma unroll
  for (int r = 0; r < 16; ++r) xW1[(size_t)(t0 + r) * DHID + j] = acc[r];
}

// ---------------- persistent RNN, DPP-systolic register dataflow ----------------
// 48 WGs x 256 thr. WG 0..31: layer1 (32 cols each). WG 32..47: layer2.
// lane l = 16r + i of wave w polls k-quad 4*tid = 256w + 64r + 4i.
// Lane accumulates cols c0+i and c0+i+16 over its row's 64 k via rotation.
__global__ __launch_bounds__(256, 1) void k_rnn(const float* __restrict__ xW1,
                                                const float* __restrict__ U1,
                                                const float* __restrict__ W2,
                                                const float* __restrict__ U2,
                                                const float* __restrict__ b2,
                                                float* __restrict__ h1v,
                                                float* __restrict__ h2v,
                                                float* __restrict__ h2buf) {
  __shared__ float cmb[2][160];   // [parity][col*5 + wave], stride-5 pad
  const int tid = threadIdx.x;
  const int wg = blockIdx.x;
  const int l = tid & 63, w = tid >> 6;
  const int r = l >> 4, i = l & 15;

  if (wg < 32) {  // ---- layer 1: h1[t] = tanh(xW1[t] + h1[t-1]@U1) ----
    const int c0 = wg * 32;
    // pre-permuted weights: wA[4j+e] = U1[256w+64r+4*((i-j)&15)+e][c0+i]
    float wA[64], wB[64];
#pragma unroll
    for (int j = 0; j < 16; ++j) {
      int sl = (i - j) & 15;
      const float* up = U1 + (size_t)(256 * w + 64 * r + 4 * sl) * DHID + c0;
#pragma unroll
      for (int e = 0; e < 4; ++e) {
        wA[4 * j + e] = up[(size_t)e * DHID + i];
        wB[4 * j + e] = up[(size_t)e * DHID + i + 16];
      }
    }
    for (int st = 0; st < TSEQ; ++st) {
      float xv = 0.f;
      if (w == 0) xv = xW1[(size_t)st * DHID + c0 + (l & 31)];
      f32x4 h;
      {
        const float* sp = h1v + (size_t)st * DHID + 4 * tid;
        while (true) { h = llc_ld16(sp); if (okq(h)) break; }
      }
      float a0 = 0.f, a1 = 0.f;
#pragma unroll
      for (int j = 0; j < 16; ++j) {
        a0 += h.x * wA[4 * j + 0]; a1 += h.x * wB[4 * j + 0];
        a0 += h.y * wA[4 * j + 1]; a1 += h.y * wB[4 * j + 1];
        a0 += h.z * wA[4 * j + 2]; a1 += h.z * wB[4 * j + 2];
        a0 += h.w * wA[4 * j + 3]; a1 += h.w * wB[4 * j + 3];
        if (j < 15) h = rotq(h);
      }
      a0 += __shfl_xor(a0, 16); a0 += __shfl_xor(a0, 32);
      a1 += __shfl_xor(a1, 16); a1 += __shfl_xor(a1, 32);
      const int par = st & 1;
      if (l < 16) {
        cmb[par][i * 5 + w] = a0;
        cmb[par][(i + 16) * 5 + w] = a1;
      }
      __syncthreads();
      if (w == 0) {
        const float* cp = &cmb[par][(l & 31) * 5];
        float s4 = (cp[0] + cp[1]) + (cp[2] + cp[3]);
        float hv = tanh_fast(xv + s4);
        float g1 = __shfl_down(hv, 1);
        float g2 = __shfl_down(hv, 2);
        float g3 = __shfl_down(hv, 3);
        if (l < 32 && (l & 3) == 0) {
          f32x4 o; o.x = hv; o.y = g1; o.z = g2; o.w = g3;
          llc_st16(h1v + (size_t)(st + 1) * DHID + c0 + l, o);
        }
      }
    }
  } else {  // ---- layer 2: h2[j] = tanh(h1[j]@W2 + h2[j-1]@U2 + b2) ----
    const int c0 = (wg - 32) * 32;
    // phase A (h1 region, W2): all waves. phase B (h2 region, U2): waves 0-1.
    float qAA[64], qAB[64], qBA[64], qBB[64];
#pragma unroll
    for (int j = 0; j < 16; ++j) {
      int sl = (i - j) & 15;
      const float* mp = W2 + (size_t)(256 * w + 64 * r + 4 * sl) * DEMB + c0;
#pragma unroll
      for (int e = 0; e < 4; ++e) {
        qAA[4 * j + e] = mp[(size_t)e * DEMB + i];
        qAB[4 * j + e] = mp[(size_t)e * DEMB + i + 16];
      }
    }
    if (w < 2) {
#pragma unroll
      for (int j = 0; j < 16; ++j) {
        int sl = (i - j) & 15;
        const float* mp = U2 + (size_t)(256 * w + 64 * r + 4 * sl) * DEMB + c0;
#pragma unroll
        for (int e = 0; e < 4; ++e) {
          qBA[4 * j + e] = mp[(size_t)e * DEMB + i];
          qBB[4 * j + e] = mp[(size_t)e * DEMB + i + 16];
        }
      }
    }
    float bias = 0.f;
    if (w == 0) bias = b2[c0 + (l & 31)];
    for (int t = 0; t < TSEQ; ++t) {
      f32x4 hA, hB;
      const float* spA = h1v + (size_t)(t + 1) * DHID + 4 * tid;
      if (w < 2) {
        const float* spB = h2v + (size_t)t * DEMB + 4 * tid;  // tid<128
        while (true) {
          f32x4 xa, xb;
          llc_ld16x2(spA, spB, xa, xb);
          if (okq(xa) && okq(xb)) { hA = xa; hB = xb; break; }
        }
      } else {
        while (true) { f32x4 xa = llc_ld16(spA); if (okq(xa)) { hA = xa; break; } }
      }
      float a0 = 0.f, a1 = 0.f;
#pragma unroll
      for (int j = 0; j < 16; ++j) {
        a0 += hA.x * qAA[4 * j + 0]; a1 += hA.x * qAB[4 * j + 0];
        a0 += hA.y * qAA[4 * j + 1]; a1 += hA.y * qAB[4 * j + 1];
        a0 += hA.z * qAA[4 * j + 2]; a1 += hA.z * qAB[4 * j + 2];
        a0 += hA.w * qAA[4 * j + 3]; a1 += hA.w * qAB[4 * j + 3];
        if (j < 15) hA = rotq(hA);
      }
      if (w < 2) {
#pragma unroll
        for (int j = 0; j < 16; ++j) {
          a0 += hB.x * qBA[4 * j + 0]; a1 += hB.x * qBB[4 * j + 0];
          a0 += hB.y * qBA[4 * j + 1]; a1 += hB.y * qBB[4 * j + 1];
          a0 += hB.z * qBA[4 * j + 2]; a1 += hB.z * qBB[4 * j + 2];
          a0 += hB.w * qBA[4 * j + 3]; a1 += hB.w * qBB[4 * j + 3];
          if (j < 15) hB = rotq(hB);
        }
      }
      a0 += __shfl_xor(a0, 16); a0 += __shfl_xor(a0, 32);
      a1 += __shfl_xor(a1, 16); a1 += __shfl_xor(a1, 32);
      const int par = t & 1;
      if (l < 16) {
        cmb[par][i * 5 + w] = a0;
        cmb[par][(i + 16) * 5 + w] = a1;
      }
      __syncthreads();
      if (w == 0) {
        const float* cp = &cmb[par][(l & 31) * 5];
        float s4 = (cp[0] + cp[1]) + (cp[2] + cp[3]);
        float hv = tanh_fast(s4 + bias);
        float g1 = __shfl_down(hv, 1);
        float g2 = __shfl_down(hv, 2);
        float g3 = __shfl_down(hv, 3);
        if (l < 32 && (l & 3) == 0) {
          f32x4 o; o.x = hv; o.y = g1; o.z = g2; o.w = g3;
          llc_st16(h2v + (size_t)(t + 1) * DEMB + c0 + l, o);
          *(f32x4*)(h2buf + (size_t)(t + 1) * DEMB + c0 + l) = o;
        }
      }
    }
  }
}

// ---------------- f32 -> bf16 casts (embedding + h2 history) ----------------
__global__ void k_conv(const float* __restrict__ emb, const float* __restrict__ h2f,
                       unsigned short* __restrict__ embB, unsigned short* __restrict__ h2b) {
  const int n1 = NVOCAB * DEMB / 4;
  const int n2 = TSEQ * DEMB / 4;
  const int stride = gridDim.x * blockDim.x;
  for (int i = blockIdx.x * blockDim.x + threadIdx.x; i < n1 + n2; i += stride) {
    float4 v;
    if (i < n1) v = ((const float4*)emb)[i];
    else        v = ((const float4*)h2f)[i - n1];
    ushort4 o;
    o.x = f2bf(v.x); o.y = f2bf(v.y); o.z = f2bf(v.z); o.w = f2bf(v.w);
    if (i < n1) ((ushort4*)embB)[i] = o;
    else        ((ushort4*)h2b)[i - n1] = o;
  }
}

// ---------------- fused logits GEMM + online softmax stats ----------------
__global__ __launch_bounds__(256, 1) void k_logits(const unsigned short* __restrict__ Ab,
                                                   const unsigned short* __restrict__ Bb,
                                                   float* __restrict__ pmax,
                                                   float* __restrict__ psum) {
  extern __shared__ char smem_dyn[];
  unsigned short* As = (unsigned short*)smem_dyn;       // 128*512*2 = 131072 B
  float* sstat = (float*)(smem_dyn + 131072);           // 4*128*2 f32
  const int tid = threadIdx.x;
  const int rb = blockIdx.x >> 4, ch = blockIdx.x & 15;
  const int r0 = rb * 128, v0 = ch * 2000;
  for (int idx = tid; idx < 128 * 64; idx += 256) {
    int row = idx >> 6, kq = idx & 63;
    uint4 v = *(const uint4*)(Ab + (size_t)(r0 + row) * DEMB + kq * 8);
    int byte = (row * 1024 + kq * 16) ^ ((row & 7) << 4);
    *(uint4*)((char*)As + byte) = v;
  }
  __syncthreads();
  const int wv = tid >> 6, lane = tid & 63;
  const int col = lane & 15, kg = lane >> 4;
  f32x4 rmax[8], rsum[8];
#pragma unroll
  for (int t = 0; t < 8; ++t) { rmax[t] = (f32x4)(-3.0e38f); rsum[t] = (f32x4)(0.f); }

  for (int strip = wv; strip < 125; strip += 4) {
    const unsigned short* bp = Bb + (size_t)(v0 + strip * 16 + col) * DEMB + kg * 8;
    f32x4 acc[8];
#pragma unroll
    for (int t = 0; t < 8; ++t) acc[t] = (f32x4)(0.f);
#pragma unroll
    for (int ks = 0; ks < 16; ++ks) {
      short8 bfrag = *(const short8*)(bp + ks * 32);
#pragma unroll
      for (int t = 0; t < 8; ++t) {
        int row = t * 16 + col;
        int byte = (row * 1024 + ks * 64 + kg * 16) ^ ((row & 7) << 4);
        short8 afrag = *(const short8*)((const char*)As + byte);
        acc[t] = __builtin_amdgcn_mfma_f32_16x16x32_bf16(afrag, bfrag, acc[t], 0, 0, 0);
      }
    }
#pragma unroll
    for (int t = 0; t < 8; ++t) {
      f32x4 v = acc[t];
      f32x4 mx = v;
#pragma unroll
      for (int d = 1; d < 16; d <<= 1) {
        mx.x = fmaxf(mx.x, __shfl_xor(mx.x, d));
        mx.y = fmaxf(mx.y, __shfl_xor(mx.y, d));
        mx.z = fmaxf(mx.z, __shfl_xor(mx.z, d));
        mx.w = fmaxf(mx.w, __shfl_xor(mx.w, d));
      }
      f32x4 nm;
      nm.x = fmaxf(rmax[t].x, mx.x);
      nm.y = fmaxf(rmax[t].y, mx.y);
      nm.z = fmaxf(rmax[t].z, mx.z);
      nm.w = fmaxf(rmax[t].w, mx.w);
      f32x4 e;
      e.x = __expf(v.x - nm.x); e.y = __expf(v.y - nm.y);
      e.z = __expf(v.z - nm.z); e.w = __expf(v.w - nm.w);
#pragma unroll
      for (int d = 1; d < 16; d <<= 1) {
        e.x += __shfl_xor(e.x, d);
        e.y += __shfl_xor(e.y, d);
        e.z += __shfl_xor(e.z, d);
        e.w += __shfl_xor(e.w, d);
      }
      rsum[t].x = rsum[t].x * __expf(rmax[t].x - nm.x) + e.x;
      rsum[t].y = rsum[t].y * __expf(rmax[t].y - nm.y) + e.y;
      rsum[t].z = rsum[t].z * __expf(rmax[t].z - nm.z) + e.z;
      rsum[t].w = rsum[t].w * __expf(rmax[t].w - nm.w) + e.w;
      rmax[t] = nm;
    }
  }
  if (col == 0) {
#pragma unroll
    for (int t = 0; t < 8; ++t) {
#pragma unroll
      for (int r = 0; r < 4; ++r) {
        int row = t * 16 + kg * 4 + r;
        sstat[(wv * 128 + row) * 2 + 0] = rmax[t][r];
        sstat[(wv * 128 + row) * 2 + 1] = rsum[t][r];
      }
    }
  }
  __syncthreads();
  if (tid < 128) {
    float m = -3.0e38f, ssum = 0.f;
#pragma unroll
    for (int w2 = 0; w2 < 4; ++w2) {
      float pm = sstat[(w2 * 128 + tid) * 2 + 0];
      float ps = sstat[(w2 * 128 + tid) * 2 + 1];
      float nm2 = fmaxf(m, pm);
      ssum = ssum * __expf(m - nm2) + ps * __expf(pm - nm2);
      m = nm2;
    }
    pmax[(size_t)(r0 + tid) * 16 + ch] = m;
    psum[(size_t)(r0 + tid) * 16 + ch] = ssum;
  }
}

// ---------------- target logit in f32: dot(h2[t], emb[tok[t]]) ----------------
__global__ __launch_bounds__(256) void k_tlogit(const int* __restrict__ tok,
                                                const float* __restrict__ emb,
                                                const float* __restrict__ h2buf,
                                                float* __restrict__ tlog) {
  const int wv = threadIdx.x >> 6, lane = threadIdx.x & 63;
  const int wgid = blockIdx.x * 4 + wv;
  for (int t = wgid; t < TSEQ; t += 128) {
    const float* hp = h2buf + (size_t)(t + 1) * DEMB + lane * 8;
    const float* ep = emb + (size_t)tok[t] * DEMB + lane * 8;
    float4 h0 = *(const float4*)hp, h1v = *(const float4*)(hp + 4);
    float4 e0 = *(const float4*)ep, e1v = *(const float4*)(ep + 4);
    float d = h0.x * e0.x + h0.y * e0.y + h0.z * e0.z + h0.w * e0.w +
              h1v.x * e1v.x + h1v.y * e1v.y + h1v.z * e1v.z + h1v.w * e1v.w;
    for (int m = 1; m < 64; m <<= 1) d += __shfl_xor(d, m);
    if (lane == 0) tlog[t] = d;
  }
}

// ---------------- final: sum_t (tlogit - lse) ----------------
__global__ void k_final(const float* __restrict__ pmax, const float* __restrict__ psum,
                        const float* __restrict__ tlog, float* __restrict__ out) {
  __shared__ float red[4];
  float local = 0.f;
  for (int t = threadIdx.x; t < TSEQ; t += 256) {
    float m = -3.0e38f, s = 0.f;
#pragma unroll
    for (int c = 0; c < 16; ++c) {
      float pm = pmax[t * 16 + c], ps = psum[t * 16 + c];
      float nm = fmaxf(m, pm);
      s = s * __expf(m - nm) + ps * __expf(pm - nm);
      m = nm;
    }
    local += tlog[t] - (m + __logf(s));
  }
  for (int d = 1; d < 64; d <<= 1) local += __shfl_xor(local, d);
  if ((threadIdx.x & 63) == 0) red[threadIdx.x >> 6] = local;
  __syncthreads();
  if (threadIdx.x == 0) out[0] = red[0] + red[1] + red[2] + red[3];
}

// ---------------- host ----------------
extern "C" void kernel_launch(void* const* d_in, const int* in_sizes, int n_in,
                              void* d_out, int out_size, void* d_ws, size_t ws_size,
                              hipStream_t stream) {
  (void)in_sizes; (void)n_in; (void)out_size; (void)ws_size;
  const int*   tok = (const int*)d_in[0];
  const float* emb = (const float*)d_in[1];
  const float* W1  = (const float*)d_in[2];
  const float* U1  = (const float*)d_in[3];
  const float* b1  = (const float*)d_in[4];
  const float* W2  = (const float*)d_in[5];
  const float* U2  = (const float*)d_in[6];
  const float* b2  = (const float*)d_in[7];
  float* out = (float*)d_out;

  char* ws = (char*)d_ws;
  size_t off = 0;
  auto alloc = [&](size_t bytes) {
    char* p = ws + off;
    off = (off + bytes + 255) & ~(size_t)255;
    return p;
  };
  float* h2buf = (float*)alloc((size_t)(TSEQ + 1) * DEMB * 4);
  unsigned short* h2b = (unsigned short*)alloc((size_t)TSEQ * DEMB * 2);
  float* pmax = (float*)alloc((size_t)TSEQ * 16 * 4);
  float* psum = (float*)alloc((size_t)TSEQ * 16 * 4);
  float* tlog = (float*)alloc((size_t)TSEQ * 4);
  // big region: [h2v][h1v][xW1] during k_rnn; embB (32.77MB) overlays from
  // offset 0 afterwards. Safe because k_init re-poisons all h slots at the
  // start of every launch before k_rnn runs.
  size_t sz_h2v = (size_t)(TSEQ + 1) * DEMB * 4;   //  4,196,352
  size_t sz_h1v = (size_t)(TSEQ + 1) * DHID * 4;   //  8,392,704
  size_t sz_xw1 = (size_t)TSEQ * DHID * 4;         //  8,388,608
  size_t sz_embB = (size_t)NVOCAB * DEMB * 2;      // 32,768,000
  size_t big_sz = sz_h2v + sz_h1v + sz_xw1;
  if (sz_embB > big_sz) big_sz = sz_embB;
  char* big = alloc(big_sz);
  float* h2v = (float*)big;
  float* h1v = (float*)(big + sz_h2v);
  float* xW1 = (float*)(big + sz_h2v + sz_h1v);
  unsigned short* embB = (unsigned short*)big;

  k_init<<<dim3(512), dim3(256), 0, stream>>>((uint4*)h1v, (uint4*)h2v);
  k_xw1<<<dim3(512), dim3(256), 0, stream>>>(tok, emb, W1, b1, xW1);
  k_rnn<<<dim3(48), dim3(256), 0, stream>>>(xW1, U1, W2, U2, b2, h1v, h2v, h2buf);
  k_conv<<<dim3(2048), dim3(256), 0, stream>>>(emb, h2buf + DEMB, embB, h2b);
  k_logits<<<dim3(256), dim3(256), 135168, stream>>>(h2b, embB, pmax, psum);
  k_tlogit<<<dim3(32), dim3(256), 0, stream>>>(tok, emb, h2buf, tlog);
  k_final<<<dim3(1), dim3(256), 0, stream>>>(pmax, psum, tlog, out);
}